// Round 8
// baseline (451.879 us; speedup 1.0000x reference)
//
#include <hip/hip_runtime.h>
#include <hip/hip_bf16.h>
#include <cstdint>
#include <cstddef>

// Problem constants
#define BB   512
#define NN   100
#define HH   768
#define II   1536
#define MM   (BB*NN)          // 51200 rows

typedef __bf16 bf16;
typedef __bf16 bf16x8 __attribute__((ext_vector_type(8)));
typedef float  f32x4  __attribute__((ext_vector_type(4)));

// async global -> LDS, 16B per lane (wave-uniform LDS base + lane*16)
__device__ __forceinline__ void gld_lds16(const void* g, void* l) {
    __builtin_amdgcn_global_load_lds(
        (const __attribute__((address_space(1))) void*)g,
        (__attribute__((address_space(3))) void*)l, 16, 0, 0);
}

// 16-lane-group sum via DPP row_ror rotate-accumulate (VALU pipe, no DS).
template <int CTRL>
__device__ __forceinline__ float ror_add(float x) {
    int y = __builtin_amdgcn_update_dpp(0, __float_as_int(x), CTRL, 0xF, 0xF, false);
    return x + __int_as_float(y);
}
__device__ __forceinline__ float red16(float x) {
    x = ror_add<0x121>(x);    // row_ror:1
    x = ror_add<0x122>(x);    // row_ror:2
    x = ror_add<0x124>(x);    // row_ror:4
    x = ror_add<0x128>(x);    // row_ror:8
    return x;
}

// Fast exact-GELU: erf via Abramowitz-Stegun 7.1.26 (|err| <= 1.5e-7)
__device__ __forceinline__ float fast_gelu(float x) {
    const float ax = fabsf(x) * 0.70710678118654752f;   // |x|/sqrt(2)
    const float t  = __builtin_amdgcn_rcpf(fmaf(0.3275911f, ax, 1.0f));
    float p = fmaf(1.061405429f, t, -1.453152027f);
    p = fmaf(p, t, 1.421413741f);
    p = fmaf(p, t, -0.284496736f);
    p = fmaf(p, t, 0.254829592f);
    p = p * t;
    const float e    = __expf(-ax * ax);
    const float erfa = fmaf(-p, e, 1.0f);               // erf(|x|/sqrt2)
    const float erfx = copysignf(erfa, x);
    return 0.5f * x * (1.0f + erfx);
}

// ---------------------------------------------------------------------------
// prep_w: W-only prep (A conversion now fused into the GEMM).
//  bid <  576 : W1 fp32 [768][1536] -> Wp bf16 [1536][768], transposed,
//               per-row chunk-XOR swizzle: stored 16B-chunk position p of
//               row n holds content chunk (p&~7)|((p&7)^(n&7)).
//  bid == 576 : gw = gamma*W2
//  bid == 577 : scal = {sum gamma*W2, sum beta*W2 + b2}
// ---------------------------------------------------------------------------
__global__ __launch_bounds__(256) void prep_w(
    const float* __restrict__ W1, const float* __restrict__ gamma,
    const float* __restrict__ beta, const float* __restrict__ W2,
    const float* __restrict__ b2,
    bf16* __restrict__ Wp, float* __restrict__ gw, float* __restrict__ scal)
{
    const int bid = blockIdx.x;
    if (bid < 576) {
        // W1 transpose+convert+swizzle: thread -> one 16B output chunk
        const int t = bid * 256 + threadIdx.x;             // 0..147455
        const int n = t % II;                              // lane-consecutive
        const int g = t / II;                              // content chunk 0..95
        const int p = (g & ~7) | ((g & 7) ^ (n & 7));
        bf16x8 o;
        #pragma unroll
        for (int i = 0; i < 8; ++i)
            o[i] = (bf16)W1[(size_t)(g * 8 + i) * II + n]; // coalesced reads
        *(bf16x8*)&Wp[(size_t)n * HH + p * 8] = o;
    } else if (bid == 576) {
        for (int j = threadIdx.x; j < II; j += 256)
            gw[j] = gamma[j] * W2[j];
    } else {
        float s1 = 0.f, s2 = 0.f;
        for (int j = threadIdx.x; j < II; j += 256) {
            float w2 = W2[j];
            s1 += gamma[j] * w2;
            s2 += beta[j]  * w2;
        }
        #pragma unroll
        for (int off = 32; off; off >>= 1) {
            s1 += __shfl_down(s1, off, 64);
            s2 += __shfl_down(s2, off, 64);
        }
        __shared__ float a1[4], a2[4];
        int lane = threadIdx.x & 63, w = threadIdx.x >> 6;
        if (lane == 0) { a1[w] = s1; a2[w] = s2; }
        __syncthreads();
        if (threadIdx.x == 0) {
            scal[0] = a1[0] + a1[1] + a1[2] + a1[3];
            scal[1] = a2[0] + a2[1] + a2[2] + a2[3] + b2[0];
        }
    }
}

// ---------------------------------------------------------------------------
// gemm_part: m97 structure (R7-proven sync), A-CONVERSION FUSED.
// 128x128 tile, BK=64, 16x16x32 bf16 MFMA, single-buffered LDS.
// A staged as FP32 straight from v_emb via global_load_lds with the XOR
// swizzle applied to the per-lane GLOBAL SOURCE address (m173 pattern:
// linear LDS dest, permuted source within aligned 128B groups) -> no
// separate conversion pass, no Av intermediate (-60 us wall, -158 MB HBM).
// Fragments: 2x ds_read_b128 fp32 + pack-cvt -> bf16x8 per A-frag.
// B staged from pre-baked Wp as before. LDS: As 32K + Bs 16K + sred 3K
// = 51 KB -> 3 blocks/CU. mb belongs to exactly one XCD (lin/12 mapping),
// so the fp32 A panel (384 KB) is read from HBM once then L2-served for
// all 12 nb-blocks. Epilogue unchanged (GELU + DPP row-reduce).
// ---------------------------------------------------------------------------
__global__ __launch_bounds__(256) void gemm_part(
    const float* __restrict__ Af, const bf16* __restrict__ Wp,
    const float* __restrict__ b1, const float* __restrict__ gw,
    float* __restrict__ part)
{
    __shared__ float AsF[128 * 64];     // 32 KB (fp32 A tile)
    __shared__ bf16  Bs[128 * 64];      // 16 KB
    __shared__ float sred[2][128][3];   // 3 KB

    const int tid  = threadIdx.x;
    // 4800 blocks = 8 XCDs x 600; 600 = 50 mb-groups x 12 nb
    const int lin  = (blockIdx.x & 7) * 600 + (blockIdx.x >> 3);
    const int mb   = lin / 12;
    const int nb   = lin % 12;
    const int lane = tid & 63;
    const int w    = tid >> 6;
    const int wm   = w >> 1;            // 0..1
    const int wn   = w & 1;             // 0..1
    const int m15  = lane & 15;
    const int q    = lane >> 4;         // 0..3
    const int row0 = mb * 128;

    // ---- A staging (fp32): call i covers rows i*16..i*16+15 of the tile.
    // thread t: row-in-call = t>>4, stored chunk c = t&15 (16B granules).
    // source chunk = (c&8)|((c&7)^(row&7))  -- XOR within 128B groups,
    // key row&7 == (t>>4)&7 (call offset i*16 is 0 mod 8).
    const int arow = tid >> 4;                          // 0..15
    const int ac   = tid & 15;
    const int acs  = (ac & 8) | ((ac & 7) ^ (arow & 7));
    const float* aPf = Af + (size_t)(row0 + arow) * HH + acs * 4;
    float* asD = AsF + tid * 4;         // call i adds i*1024 floats (4 KB)

    // ---- B staging (bf16, baked swizzle): as in R7
    const int srow = tid >> 3;          // 0..31
    const int sc   = tid & 7;
    const bf16* bP = Wp + (size_t)(nb * 128 + srow) * HH + sc * 8;
    bf16* bsD = Bs + tid * 8;           // call i adds i*2048 elems (4 KB)

    f32x4 acc[4][4] = {};

    for (int kt = 0; kt < 12; ++kt) {
        // ---- stage K-tile kt: A fp32 (8 calls), B bf16 (4 calls) ----
        const float* ak = aPf + kt * 64;
        const bf16*  bk = bP  + kt * 64;
        #pragma unroll
        for (int i = 0; i < 8; ++i)
            gld_lds16(ak + (size_t)(16 * i) * HH, asD + i * 1024);
        #pragma unroll
        for (int i = 0; i < 4; ++i)
            gld_lds16(bk + (size_t)(32 * i) * HH, bsD + i * 2048);
        asm volatile("s_waitcnt vmcnt(0)" ::: "memory");
        __syncthreads();

        // ---- compute: 2 kb-phases over the 64-wide tile ----
        #pragma unroll
        for (int kb = 0; kb < 2; ++kb) {
            const int xb = ((kb * 4 + q) ^ (m15 & 7)) * 8;   // B swizzle (elems)
            const int p0 = (2 * q) ^ (m15 & 7);              // A chunk pos
            bf16x8 af[4];
            #pragma unroll
            for (int mt = 0; mt < 4; ++mt) {
                const int r = wm*64 + mt*16 + m15;
                const f32x4* Arow = (const f32x4*)&AsF[r*64 + kb*32];
                f32x4 lo = Arow[p0];
                f32x4 hi = Arow[p0 ^ 1];
                af[mt] = (bf16x8){ (bf16)lo[0],(bf16)lo[1],(bf16)lo[2],(bf16)lo[3],
                                   (bf16)hi[0],(bf16)hi[1],(bf16)hi[2],(bf16)hi[3] };
            }
            #pragma unroll
            for (int nt = 0; nt < 4; ++nt) {
                bf16x8 bfr = *(const bf16x8*)&Bs[(wn*64 + nt*16 + m15)*64 + xb];
                #pragma unroll
                for (int mt = 0; mt < 4; ++mt)
                    acc[mt][nt] = __builtin_amdgcn_mfma_f32_16x16x32_bf16(
                        af[mt], bfr, acc[mt][nt], 0, 0, 0);
            }
        }
        __syncthreads();
    }

    // ---- epilogue: +b1, fast GELU, per-row partial stats over 128 cols ----
    float bv[4], gv[4];
    #pragma unroll
    for (int nt = 0; nt < 4; ++nt) {
        const int col = nb*128 + wn*64 + nt*16 + m15;
        bv[nt] = b1[col];
        gv[nt] = gw[col];
    }

    #pragma unroll
    for (int mt = 0; mt < 4; ++mt) {
        #pragma unroll
        for (int r = 0; r < 4; ++r) {
            float x0 = 0.f, x1 = 0.f, x2 = 0.f;
            #pragma unroll
            for (int nt = 0; nt < 4; ++nt) {
                // C/D layout: col = lane&15, row = q*4 + r
                float g = fast_gelu(acc[mt][nt][r] + bv[nt]);
                x0 += g; x1 += g * g; x2 += g * gv[nt];
            }
            x0 = red16(x0); x1 = red16(x1); x2 = red16(x2);
            if (m15 == 0) {
                const int rl = wm*64 + mt*16 + q*4 + r;   // 0..127
                sred[wn][rl][0] = x0;
                sred[wn][rl][1] = x1;
                sred[wn][rl][2] = x2;
            }
        }
    }
    __syncthreads();

    if (tid < 128) {
        const size_t rg = (size_t)row0 + tid;
        #pragma unroll
        for (int s = 0; s < 3; ++s)
            part[(size_t)s * 12 * MM + (size_t)nb * MM + rg]
                = sred[0][tid][s] + sred[1][tid][s];
    }
}

// ---------------------------------------------------------------------------
// score_pred: finish LN + sigmoid for the 100 rows of batch b, write scores,
// then pred = sum(scores), logits = one_hot(clamp(round(pred),0,15))
// ---------------------------------------------------------------------------
__global__ __launch_bounds__(128) void score_pred(
    const float* __restrict__ part, const float* __restrict__ scal,
    float* __restrict__ o_scores, float* __restrict__ o_pred,
    float* __restrict__ o_logits)
{
    const int b = blockIdx.x, t = threadIdx.x;
    float s = 0.f;
    if (t < NN) {
        const size_t row = (size_t)b * NN + t;
        float Sh = 0.f, Shh = 0.f, Shg = 0.f;
        #pragma unroll
        for (int j = 0; j < 12; ++j) {
            Sh  += part[(size_t)0*12*MM + (size_t)j*MM + row];
            Shh += part[(size_t)1*12*MM + (size_t)j*MM + row];
            Shg += part[(size_t)2*12*MM + (size_t)j*MM + row];
        }
        const float mu   = Sh * (1.0f / II);
        const float var  = Shh * (1.0f / II) - mu * mu;
        const float rstd = rsqrtf(var + 1e-5f);
        const float z    = rstd * (Shg - mu * scal[0]) + scal[1];
        s = 1.0f / (1.0f + __expf(-z));
        o_scores[row] = s;
    }
    float v = s;
    #pragma unroll
    for (int off = 32; off; off >>= 1) v += __shfl_down(v, off, 64);
    __shared__ float ssum[2];
    const int lane = t & 63, w = t >> 6;
    if (lane == 0) ssum[w] = v;
    __syncthreads();
    const float p = ssum[0] + ssum[1];
    if (t == 0) o_pred[b] = p;
    if (t < 16) {
        int aid = (int)rintf(p);
        aid = aid < 0 ? 0 : (aid > 15 ? 15 : aid);
        o_logits[b * 16 + t] = (t == aid) ? 1.0f : 0.0f;
    }
}

// ---------------------------------------------------------------------------
extern "C" void kernel_launch(void* const* d_in, const int* in_sizes, int n_in,
                              void* d_out, int out_size, void* d_ws, size_t ws_size,
                              hipStream_t stream)
{
    const float* v_emb = (const float*)d_in[0];
    const float* W1    = (const float*)d_in[1];
    const float* b1    = (const float*)d_in[2];
    const float* gamma = (const float*)d_in[3];
    const float* beta  = (const float*)d_in[4];
    const float* W2    = (const float*)d_in[5];
    const float* b2    = (const float*)d_in[6];

    char* ws = (char*)d_ws;
    size_t off = 0;
    bf16*  Wp   = (bf16*)(ws + off);  off += (size_t)II * HH * 2;      // 2.36 MB
    float* gw   = (float*)(ws + off); off += (size_t)II * 4;
    float* scal = (float*)(ws + off); off += 256;
    float* part = (float*)(ws + off); off += (size_t)MM * 36 * 4;      // 7.37 MB

    float* out       = (float*)d_out;
    float* o_scores  = out;            // 51200
    float* o_pred    = out + MM;       // 512
    float* o_logits  = out + MM + BB;  // 8192

    hipLaunchKernelGGL(prep_w, dim3(578), dim3(256), 0, stream,
                       W1, gamma, beta, W2, b2, Wp, gw, scal);
    hipLaunchKernelGGL(gemm_part, dim3((MM / 128) * 12), dim3(256),
                       0, stream, v_emb, Wp, b1, gw, part);
    hipLaunchKernelGGL(score_pred, dim3(BB), dim3(128), 0, stream,
                       part, scal, o_scores, o_pred, o_logits);
}

// Round 9
// 423.418 us; speedup vs baseline: 1.0672x; 1.0672x over previous
//
#include <hip/hip_runtime.h>
#include <hip/hip_bf16.h>
#include <cstdint>
#include <cstddef>

// Problem constants
#define BB   512
#define NN   100
#define HH   768
#define II   1536
#define MM   (BB*NN)          // 51200 rows

typedef __bf16 bf16;
typedef __bf16 bf16x8 __attribute__((ext_vector_type(8)));
typedef float  f32x4  __attribute__((ext_vector_type(4)));

// async global -> LDS, 16B per lane (wave-uniform LDS base + lane*16)
__device__ __forceinline__ void gld_lds16(const void* g, void* l) {
    __builtin_amdgcn_global_load_lds(
        (const __attribute__((address_space(1))) void*)g,
        (__attribute__((address_space(3))) void*)l, 16, 0, 0);
}

// 16-lane-group sum via DPP row_ror rotate-accumulate (VALU pipe, no DS).
template <int CTRL>
__device__ __forceinline__ float ror_add(float x) {
    int y = __builtin_amdgcn_update_dpp(0, __float_as_int(x), CTRL, 0xF, 0xF, false);
    return x + __int_as_float(y);
}
__device__ __forceinline__ float red16(float x) {
    x = ror_add<0x121>(x);    // row_ror:1
    x = ror_add<0x122>(x);    // row_ror:2
    x = ror_add<0x124>(x);    // row_ror:4
    x = ror_add<0x128>(x);    // row_ror:8
    return x;
}

// Fast exact-GELU: erf via Abramowitz-Stegun 7.1.26 (|err| <= 1.5e-7)
__device__ __forceinline__ float fast_gelu(float x) {
    const float ax = fabsf(x) * 0.70710678118654752f;   // |x|/sqrt(2)
    const float t  = __builtin_amdgcn_rcpf(fmaf(0.3275911f, ax, 1.0f));
    float p = fmaf(1.061405429f, t, -1.453152027f);
    p = fmaf(p, t, 1.421413741f);
    p = fmaf(p, t, -0.284496736f);
    p = fmaf(p, t, 0.254829592f);
    p = p * t;
    const float e    = __expf(-ax * ax);
    const float erfa = fmaf(-p, e, 1.0f);               // erf(|x|/sqrt2)
    const float erfx = copysignf(erfa, x);
    return 0.5f * x * (1.0f + erfx);
}

// ---------------------------------------------------------------------------
// prep_w: W-only prep (A conversion fused into the GEMM).
//  bid <  576 : W1 fp32 [768][1536] -> Wp bf16 [1536][768], transposed,
//               per-row chunk-XOR swizzle: stored 16B-chunk position p of
//               row n holds content chunk (p&~7)|((p&7)^(n&7)).
//  bid == 576 : gw = gamma*W2
//  bid == 577 : scal = {sum gamma*W2, sum beta*W2 + b2}
// ---------------------------------------------------------------------------
__global__ __launch_bounds__(256) void prep_w(
    const float* __restrict__ W1, const float* __restrict__ gamma,
    const float* __restrict__ beta, const float* __restrict__ W2,
    const float* __restrict__ b2,
    bf16* __restrict__ Wp, float* __restrict__ gw, float* __restrict__ scal)
{
    const int bid = blockIdx.x;
    if (bid < 576) {
        // W1 transpose+convert+swizzle: thread -> one 16B output chunk
        const int t = bid * 256 + threadIdx.x;             // 0..147455
        const int n = t % II;                              // lane-consecutive
        const int g = t / II;                              // content chunk 0..95
        const int p = (g & ~7) | ((g & 7) ^ (n & 7));
        bf16x8 o;
        #pragma unroll
        for (int i = 0; i < 8; ++i)
            o[i] = (bf16)W1[(size_t)(g * 8 + i) * II + n]; // coalesced reads
        *(bf16x8*)&Wp[(size_t)n * HH + p * 8] = o;
    } else if (bid == 576) {
        for (int j = threadIdx.x; j < II; j += 256)
            gw[j] = gamma[j] * W2[j];
    } else {
        float s1 = 0.f, s2 = 0.f;
        for (int j = threadIdx.x; j < II; j += 256) {
            float w2 = W2[j];
            s1 += gamma[j] * w2;
            s2 += beta[j]  * w2;
        }
        #pragma unroll
        for (int off = 32; off; off >>= 1) {
            s1 += __shfl_down(s1, off, 64);
            s2 += __shfl_down(s2, off, 64);
        }
        __shared__ float a1[4], a2[4];
        int lane = threadIdx.x & 63, w = threadIdx.x >> 6;
        if (lane == 0) { a1[w] = s1; a2[w] = s2; }
        __syncthreads();
        if (threadIdx.x == 0) {
            scal[0] = a1[0] + a1[1] + a1[2] + a1[3];
            scal[1] = a2[0] + a2[1] + a2[2] + a2[3] + b2[0];
        }
    }
}

// ---------------------------------------------------------------------------
// gemm_part: R7 tile/read structure (128x128, BK=64, 16x16x32 MFMA, the
// proven 0-conflict bf16 As/Bs layout), A-CONVERSION FUSED via reg-staging:
// per K-step each thread loads 8 f32x4 of v_emb (source-XOR'd within 128B
// groups), converts to 4x bf16x8, ds_write_b128 into the SAME As layout R7
// read (reads byte-identical -> 0 conflicts by construction).
// T14 split: A(kt+1) reg-loads + B(kt+1) global_load_lds (Bs double-buffered)
// issue BEFORE the barrier -> a full compute phase of latency cover.
// Sync: raw s_barrier with one counted "vmcnt(12) lgkmcnt(0)" per step
// (waits B(kt)'s 4 loads; leaves A'(8)+B'(4) in flight). As is single-buffered
// (written between barriers, like R7's staging slot). LDS 51 KB -> 3 blk/CU.
// Epilogue: +b1, fast GELU, DPP row-reduce partial LN stats.
// ---------------------------------------------------------------------------
__global__ __launch_bounds__(256) void gemm_part(
    const float* __restrict__ Af, const bf16* __restrict__ Wp,
    const float* __restrict__ b1, const float* __restrict__ gw,
    float* __restrict__ part)
{
    __shared__ bf16  As[8192];          // 16 KB (single buffer)
    __shared__ bf16  Bs[2 * 8192];      // 32 KB (double buffer)
    __shared__ float sred[2][128][3];   // 3 KB

    const int tid  = threadIdx.x;
    // 4800 blocks = 8 XCDs x 600; 600 = 50 mb-groups x 12 nb
    const int lin  = (blockIdx.x & 7) * 600 + (blockIdx.x >> 3);
    const int mb   = lin / 12;
    const int nb   = lin % 12;
    const int lane = tid & 63;
    const int w    = tid >> 6;
    const int wm   = w >> 1;            // 0..1
    const int wn   = w & 1;             // 0..1
    const int m15  = lane & 15;
    const int q    = lane >> 4;         // 0..3
    const int row0 = mb * 128;

    // staging coords (both A and B): thread t covers row srow (+32 per call),
    // chunk slot sc; A's global source chunk is XOR'd so LDS position sc of
    // row r holds content sc^(r&7) -- identical to R7's baked Av layout.
    const int srow = tid >> 3;          // 0..31
    const int sc   = tid & 7;
    const int asel = sc ^ (srow & 7);
    const float* aPf = Af + (size_t)(row0     + srow) * HH + asel * 8;
    const bf16*  bP  = Wp + (size_t)(nb * 128 + srow) * HH + sc * 8;
    bf16* asW = As + tid * 8;           // call i adds i*2048 elems
    bf16* bsW = Bs + tid * 8;           // + buf*8192, call i adds i*2048

    f32x4 av0[4], av1[4];               // in-flight A registers (32 VGPR)

#define LOADA(T) do {                                                       \
    _Pragma("unroll")                                                       \
    for (int i = 0; i < 4; ++i) {                                           \
        const float* s = aPf + (size_t)(32 * i) * HH + (T) * 64;            \
        av0[i] = *(const f32x4*)(s);                                        \
        av1[i] = *(const f32x4*)(s + 4);                                    \
    }                                                                       \
} while (0)

#define CVTWRITE() do {                                                     \
    _Pragma("unroll")                                                       \
    for (int i = 0; i < 4; ++i) {                                           \
        bf16x8 o = { (bf16)av0[i][0],(bf16)av0[i][1],                       \
                     (bf16)av0[i][2],(bf16)av0[i][3],                       \
                     (bf16)av1[i][0],(bf16)av1[i][1],                       \
                     (bf16)av1[i][2],(bf16)av1[i][3] };                     \
        *(bf16x8*)(asW + i * 2048) = o;                                     \
    }                                                                       \
} while (0)

#define STAGEB(T, BUF) do {                                                 \
    const bf16* _b = bP + (T) * 64;                                         \
    _Pragma("unroll")                                                       \
    for (int i = 0; i < 4; ++i)                                             \
        gld_lds16(_b + (size_t)(32 * i) * HH, bsW + (BUF) * 8192 + i * 2048);\
} while (0)

    f32x4 acc[4][4] = {};

    // ---- prologue: A(0) to regs, B(0) to buf 0 ----
    LOADA(0);
    STAGEB(0, 0);

    for (int kt = 0; kt < 12; ++kt) {
        const int buf = kt & 1;

        // finish A(kt): cvt + ds_write (compiler waits av; may drain B(kt)
        // too -- needed this step anyway, so harmless either way)
        CVTWRITE();

        if (kt < 11) {
            LOADA(kt + 1);              // 8 loads in flight across compute
            STAGEB(kt + 1, buf ^ 1);    // 4 gld_lds into the other B buffer
            // wait B(kt) (4 oldest of 16 outstanding); A'(8)+B'(4) stay live
            asm volatile("s_waitcnt vmcnt(12) lgkmcnt(0)" ::: "memory");
        } else {
            asm volatile("s_waitcnt vmcnt(0) lgkmcnt(0)" ::: "memory");
        }
        __builtin_amdgcn_s_barrier();

        // ---- compute: 2 kb-phases over the 64-wide tile ----
        #pragma unroll
        for (int kb = 0; kb < 2; ++kb) {
            const int xsel = ((kb * 4 + q) ^ (m15 & 7)) * 8;
            bf16x8 af[4];
            #pragma unroll
            for (int mt = 0; mt < 4; ++mt)
                af[mt] = *(const bf16x8*)&As[(wm*64 + mt*16 + m15)*64 + xsel];
            #pragma unroll
            for (int nt = 0; nt < 4; ++nt) {
                bf16x8 bfr = *(const bf16x8*)
                    &Bs[buf*8192 + (wn*64 + nt*16 + m15)*64 + xsel];
                #pragma unroll
                for (int mt = 0; mt < 4; ++mt)
                    acc[mt][nt] = __builtin_amdgcn_mfma_f32_16x16x32_bf16(
                        af[mt], bfr, acc[mt][nt], 0, 0, 0);
            }
        }
        __builtin_amdgcn_s_barrier();
    }

#undef LOADA
#undef CVTWRITE
#undef STAGEB

    // ---- epilogue: +b1, fast GELU, per-row partial stats over 128 cols ----
    float bv[4], gv[4];
    #pragma unroll
    for (int nt = 0; nt < 4; ++nt) {
        const int col = nb*128 + wn*64 + nt*16 + m15;
        bv[nt] = b1[col];
        gv[nt] = gw[col];
    }

    #pragma unroll
    for (int mt = 0; mt < 4; ++mt) {
        #pragma unroll
        for (int r = 0; r < 4; ++r) {
            float x0 = 0.f, x1 = 0.f, x2 = 0.f;
            #pragma unroll
            for (int nt = 0; nt < 4; ++nt) {
                // C/D layout: col = lane&15, row = q*4 + r
                float g = fast_gelu(acc[mt][nt][r] + bv[nt]);
                x0 += g; x1 += g * g; x2 += g * gv[nt];
            }
            x0 = red16(x0); x1 = red16(x1); x2 = red16(x2);
            if (m15 == 0) {
                const int rl = wm*64 + mt*16 + q*4 + r;   // 0..127
                sred[wn][rl][0] = x0;
                sred[wn][rl][1] = x1;
                sred[wn][rl][2] = x2;
            }
        }
    }
    __syncthreads();

    if (tid < 128) {
        const size_t rg = (size_t)row0 + tid;
        #pragma unroll
        for (int s = 0; s < 3; ++s)
            part[(size_t)s * 12 * MM + (size_t)nb * MM + rg]
                = sred[0][tid][s] + sred[1][tid][s];
    }
}

// ---------------------------------------------------------------------------
// score_pred: finish LN + sigmoid for the 100 rows of batch b, write scores,
// then pred = sum(scores), logits = one_hot(clamp(round(pred),0,15))
// ---------------------------------------------------------------------------
__global__ __launch_bounds__(128) void score_pred(
    const float* __restrict__ part, const float* __restrict__ scal,
    float* __restrict__ o_scores, float* __restrict__ o_pred,
    float* __restrict__ o_logits)
{
    const int b = blockIdx.x, t = threadIdx.x;
    float s = 0.f;
    if (t < NN) {
        const size_t row = (size_t)b * NN + t;
        float Sh = 0.f, Shh = 0.f, Shg = 0.f;
        #pragma unroll
        for (int j = 0; j < 12; ++j) {
            Sh  += part[(size_t)0*12*MM + (size_t)j*MM + row];
            Shh += part[(size_t)1*12*MM + (size_t)j*MM + row];
            Shg += part[(size_t)2*12*MM + (size_t)j*MM + row];
        }
        const float mu   = Sh * (1.0f / II);
        const float var  = Shh * (1.0f / II) - mu * mu;
        const float rstd = rsqrtf(var + 1e-5f);
        const float z    = rstd * (Shg - mu * scal[0]) + scal[1];
        s = 1.0f / (1.0f + __expf(-z));
        o_scores[row] = s;
    }
    float v = s;
    #pragma unroll
    for (int off = 32; off; off >>= 1) v += __shfl_down(v, off, 64);
    __shared__ float ssum[2];
    const int lane = t & 63, w = t >> 6;
    if (lane == 0) ssum[w] = v;
    __syncthreads();
    const float p = ssum[0] + ssum[1];
    if (t == 0) o_pred[b] = p;
    if (t < 16) {
        int aid = (int)rintf(p);
        aid = aid < 0 ? 0 : (aid > 15 ? 15 : aid);
        o_logits[b * 16 + t] = (t == aid) ? 1.0f : 0.0f;
    }
}

// ---------------------------------------------------------------------------
extern "C" void kernel_launch(void* const* d_in, const int* in_sizes, int n_in,
                              void* d_out, int out_size, void* d_ws, size_t ws_size,
                              hipStream_t stream)
{
    const float* v_emb = (const float*)d_in[0];
    const float* W1    = (const float*)d_in[1];
    const float* b1    = (const float*)d_in[2];
    const float* gamma = (const float*)d_in[3];
    const float* beta  = (const float*)d_in[4];
    const float* W2    = (const float*)d_in[5];
    const float* b2    = (const float*)d_in[6];

    char* ws = (char*)d_ws;
    size_t off = 0;
    bf16*  Wp   = (bf16*)(ws + off);  off += (size_t)II * HH * 2;      // 2.36 MB
    float* gw   = (float*)(ws + off); off += (size_t)II * 4;
    float* scal = (float*)(ws + off); off += 256;
    float* part = (float*)(ws + off); off += (size_t)MM * 36 * 4;      // 7.37 MB

    float* out       = (float*)d_out;
    float* o_scores  = out;            // 51200
    float* o_pred    = out + MM;       // 512
    float* o_logits  = out + MM + BB;  // 8192

    hipLaunchKernelGGL(prep_w, dim3(578), dim3(256), 0, stream,
                       W1, gamma, beta, W2, b2, Wp, gw, scal);
    hipLaunchKernelGGL(gemm_part, dim3((MM / 128) * 12), dim3(256),
                       0, stream, v_emb, Wp, b1, gw, part);
    hipLaunchKernelGGL(score_pred, dim3(BB), dim3(128), 0, stream,
                       part, scal, o_scores, o_pred, o_logits);
}

// Round 10
// 390.434 us; speedup vs baseline: 1.1574x; 1.0845x over previous
//
#include <hip/hip_runtime.h>
#include <hip/hip_bf16.h>
#include <cstdint>
#include <cstddef>

// Problem constants
#define BB   512
#define NN   100
#define HH   768
#define II   1536
#define MM   (BB*NN)          // 51200 rows

typedef __bf16 bf16;
typedef __bf16 bf16x8 __attribute__((ext_vector_type(8)));
typedef float  f32x4  __attribute__((ext_vector_type(4)));
typedef float  f32x4v __attribute__((ext_vector_type(4)));

// async global -> LDS, 16B per lane (wave-uniform LDS base + lane*16)
__device__ __forceinline__ void gld_lds16(const void* g, void* l) {
    __builtin_amdgcn_global_load_lds(
        (const __attribute__((address_space(1))) void*)g,
        (__attribute__((address_space(3))) void*)l, 16, 0, 0);
}

// 16-lane-group sum via DPP row_ror rotate-accumulate (VALU pipe, no DS).
template <int CTRL>
__device__ __forceinline__ float ror_add(float x) {
    int y = __builtin_amdgcn_update_dpp(0, __float_as_int(x), CTRL, 0xF, 0xF, false);
    return x + __int_as_float(y);
}
__device__ __forceinline__ float red16(float x) {
    x = ror_add<0x121>(x);    // row_ror:1
    x = ror_add<0x122>(x);    // row_ror:2
    x = ror_add<0x124>(x);    // row_ror:4
    x = ror_add<0x128>(x);    // row_ror:8
    return x;
}

// Fast exact-GELU: erf via Abramowitz-Stegun 7.1.26 (|err| <= 1.5e-7)
__device__ __forceinline__ float fast_gelu(float x) {
    const float ax = fabsf(x) * 0.70710678118654752f;   // |x|/sqrt(2)
    const float t  = __builtin_amdgcn_rcpf(fmaf(0.3275911f, ax, 1.0f));
    float p = fmaf(1.061405429f, t, -1.453152027f);
    p = fmaf(p, t, 1.421413741f);
    p = fmaf(p, t, -0.284496736f);
    p = fmaf(p, t, 0.254829592f);
    p = p * t;
    const float e    = __expf(-ax * ax);
    const float erfa = fmaf(-p, e, 1.0f);               // erf(|x|/sqrt2)
    const float erfx = copysignf(erfa, x);
    return 0.5f * x * (1.0f + erfx);
}

// ---------------------------------------------------------------------------
// prep_conv (fused):
//  bid < 19200 : v_emb fp32 [51200][768] -> Av bf16, chunk-XOR-swizzled.
//                FLAT MAP: thread idx produces output 16B-chunk idx
//                (row m = idx/96, stored pos p = idx%96), reading content
//                chunk g = (p&~7)|((p&7)^(m&7)) -- involution within each
//                128B group, so reads stay cache-line coalesced and stores
//                are perfectly linear (4 KB per wave). NT loads keep the
//                read-once v_emb out of L3 so Av stays resident for the GEMM.
//  bid < 19776 : W1 fp32 [768][1536] -> Wp bf16 [1536][768], transposed,
//                same per-row chunk-XOR swizzle (rows = n, key n&7)
//  bid == 19776: gw = gamma*W2
//  bid == 19777: scal = {sum gamma*W2, sum beta*W2 + b2}
// ---------------------------------------------------------------------------
__global__ __launch_bounds__(256) void prep_conv(
    const float* __restrict__ v, const float* __restrict__ W1,
    const float* __restrict__ gamma, const float* __restrict__ beta,
    const float* __restrict__ W2, const float* __restrict__ b2,
    bf16* __restrict__ Av, bf16* __restrict__ Wp,
    float* __restrict__ gw, float* __restrict__ scal)
{
    const int bid = blockIdx.x;
    if (bid < 19200) {
        const int idx = bid * 256 + threadIdx.x;           // 0..4915199
        const int m_  = idx / 96;                          // row (magic-mul)
        const int p   = idx - m_ * 96;                     // stored pos 0..95
        const int g   = (p & ~7) | ((p & 7) ^ (m_ & 7));   // content chunk
        const float* src = v + (size_t)m_ * HH + g * 8;
        f32x4v a = __builtin_nontemporal_load((const f32x4v*)src);
        f32x4v b = __builtin_nontemporal_load((const f32x4v*)(src + 4));
        bf16x8 o = { (bf16)a[0],(bf16)a[1],(bf16)a[2],(bf16)a[3],
                     (bf16)b[0],(bf16)b[1],(bf16)b[2],(bf16)b[3] };
        *(bf16x8*)(Av + (size_t)idx * 8) = o;
    } else if (bid < 19776) {
        // W1 transpose+convert+swizzle: thread -> one 16B output chunk
        const int t = (bid - 19200) * 256 + threadIdx.x;   // 0..147455
        const int n = t % II;                              // lane-consecutive
        const int g = t / II;                              // content chunk 0..95
        const int p = (g & ~7) | ((g & 7) ^ (n & 7));
        bf16x8 o;
        #pragma unroll
        for (int i = 0; i < 8; ++i)
            o[i] = (bf16)W1[(size_t)(g * 8 + i) * II + n]; // coalesced reads
        *(bf16x8*)&Wp[(size_t)n * HH + p * 8] = o;
    } else if (bid == 19776) {
        for (int j = threadIdx.x; j < II; j += 256)
            gw[j] = gamma[j] * W2[j];
    } else {
        float s1 = 0.f, s2 = 0.f;
        for (int j = threadIdx.x; j < II; j += 256) {
            float w2 = W2[j];
            s1 += gamma[j] * w2;
            s2 += beta[j]  * w2;
        }
        #pragma unroll
        for (int off = 32; off; off >>= 1) {
            s1 += __shfl_down(s1, off, 64);
            s2 += __shfl_down(s2, off, 64);
        }
        __shared__ float a1[4], a2[4];
        int lane = threadIdx.x & 63, w = threadIdx.x >> 6;
        if (lane == 0) { a1[w] = s1; a2[w] = s2; }
        __syncthreads();
        if (threadIdx.x == 0) {
            scal[0] = a1[0] + a1[1] + a1[2] + a1[3];
            scal[1] = a2[0] + a2[1] + a2[2] + a2[3] + b2[0];
        }
    }
}

// ---------------------------------------------------------------------------
// gemm_part: m97-exact structure (R7-proven, 178 us). 128x128 tile, BK=64,
// 16x16x32 bf16 MFMA, SINGLE-buffered LDS (35 KB -> 4 blocks/CU),
// 2 barriers per K-step, 12 K-steps. Cross-block dephasing covers drains.
// Read xsel = ((kb*4+q) ^ (m15&7)): 2-way bank aliasing max (free).
// Epilogue: +b1, fast GELU, per-row partial LN stats via DPP row-reduce
// (VALU, off the contended DS pipe) -> part[s][nb][row].
// ---------------------------------------------------------------------------
__global__ __launch_bounds__(256) void gemm_part(
    const bf16* __restrict__ Av, const bf16* __restrict__ Wp,
    const float* __restrict__ b1, const float* __restrict__ gw,
    float* __restrict__ part)
{
    __shared__ bf16  As[128 * 64];      // 16 KB
    __shared__ bf16  Bs[128 * 64];      // 16 KB
    __shared__ float sred[2][128][3];   // 3 KB

    const int tid  = threadIdx.x;
    // 4800 blocks = 8 XCDs x 600; 600 = 50 mb-groups x 12 nb
    const int lin  = (blockIdx.x & 7) * 600 + (blockIdx.x >> 3);
    const int mb   = lin / 12;
    const int nb   = lin % 12;
    const int lane = tid & 63;
    const int w    = tid >> 6;
    const int wm   = w >> 1;            // 0..1
    const int wn   = w & 1;             // 0..1
    const int m15  = lane & 15;
    const int q    = lane >> 4;         // 0..3
    const int row0 = mb * 128;

    // staging: thread t covers (row = i*32 + t/8, chunk pos = t&7), 16B each
    const int srow = tid >> 3;          // 0..31
    const int sc   = tid & 7;
    const bf16* aP = Av + (size_t)(row0     + srow) * HH + sc * 8;
    const bf16* bP = Wp + (size_t)(nb * 128 + srow) * HH + sc * 8;
    bf16* asD = As + tid * 8;           // call i adds i*2048 elems (4 KB)
    bf16* bsD = Bs + tid * 8;

    f32x4 acc[4][4] = {};

    for (int kt = 0; kt < 12; ++kt) {
        const int ko = kt * 64;
        // ---- stage K-tile kt (A: 4 calls, B: 4 calls; 32 rows each) ----
        #pragma unroll
        for (int i = 0; i < 4; ++i)
            gld_lds16(aP + (size_t)(32 * i) * HH + ko, asD + i * 2048);
        #pragma unroll
        for (int i = 0; i < 4; ++i)
            gld_lds16(bP + (size_t)(32 * i) * HH + ko, bsD + i * 2048);
        asm volatile("s_waitcnt vmcnt(0)" ::: "memory");
        __syncthreads();

        // ---- compute: 2 kb-phases over the 64-wide tile ----
        #pragma unroll
        for (int kb = 0; kb < 2; ++kb) {
            const int xsel = ((kb * 4 + q) ^ (m15 & 7)) * 8;
            bf16x8 af[4];
            #pragma unroll
            for (int mt = 0; mt < 4; ++mt)
                af[mt] = *(const bf16x8*)&As[(wm*64 + mt*16 + m15)*64 + xsel];
            #pragma unroll
            for (int nt = 0; nt < 4; ++nt) {
                bf16x8 bfr = *(const bf16x8*)&Bs[(wn*64 + nt*16 + m15)*64 + xsel];
                #pragma unroll
                for (int mt = 0; mt < 4; ++mt)
                    acc[mt][nt] = __builtin_amdgcn_mfma_f32_16x16x32_bf16(
                        af[mt], bfr, acc[mt][nt], 0, 0, 0);
            }
        }
        __syncthreads();
    }

    // ---- epilogue: +b1, fast GELU, per-row partial stats over 128 cols ----
    float bv[4], gv[4];
    #pragma unroll
    for (int nt = 0; nt < 4; ++nt) {
        const int col = nb*128 + wn*64 + nt*16 + m15;
        bv[nt] = b1[col];
        gv[nt] = gw[col];
    }

    #pragma unroll
    for (int mt = 0; mt < 4; ++mt) {
        #pragma unroll
        for (int r = 0; r < 4; ++r) {
            float x0 = 0.f, x1 = 0.f, x2 = 0.f;
            #pragma unroll
            for (int nt = 0; nt < 4; ++nt) {
                // C/D layout: col = lane&15, row = q*4 + r
                float g = fast_gelu(acc[mt][nt][r] + bv[nt]);
                x0 += g; x1 += g * g; x2 += g * gv[nt];
            }
            x0 = red16(x0); x1 = red16(x1); x2 = red16(x2);
            if (m15 == 0) {
                const int rl = wm*64 + mt*16 + q*4 + r;   // 0..127
                sred[wn][rl][0] = x0;
                sred[wn][rl][1] = x1;
                sred[wn][rl][2] = x2;
            }
        }
    }
    __syncthreads();

    if (tid < 128) {
        const size_t rg = (size_t)row0 + tid;
        #pragma unroll
        for (int s = 0; s < 3; ++s)
            part[(size_t)s * 12 * MM + (size_t)nb * MM + rg]
                = sred[0][tid][s] + sred[1][tid][s];
    }
}

// ---------------------------------------------------------------------------
// score_pred: finish LN + sigmoid for the 100 rows of batch b, write scores,
// then pred = sum(scores), logits = one_hot(clamp(round(pred),0,15))
// ---------------------------------------------------------------------------
__global__ __launch_bounds__(128) void score_pred(
    const float* __restrict__ part, const float* __restrict__ scal,
    float* __restrict__ o_scores, float* __restrict__ o_pred,
    float* __restrict__ o_logits)
{
    const int b = blockIdx.x, t = threadIdx.x;
    float s = 0.f;
    if (t < NN) {
        const size_t row = (size_t)b * NN + t;
        float Sh = 0.f, Shh = 0.f, Shg = 0.f;
        #pragma unroll
        for (int j = 0; j < 12; ++j) {
            Sh  += part[(size_t)0*12*MM + (size_t)j*MM + row];
            Shh += part[(size_t)1*12*MM + (size_t)j*MM + row];
            Shg += part[(size_t)2*12*MM + (size_t)j*MM + row];
        }
        const float mu   = Sh * (1.0f / II);
        const float var  = Shh * (1.0f / II) - mu * mu;
        const float rstd = rsqrtf(var + 1e-5f);
        const float z    = rstd * (Shg - mu * scal[0]) + scal[1];
        s = 1.0f / (1.0f + __expf(-z));
        o_scores[row] = s;
    }
    float v = s;
    #pragma unroll
    for (int off = 32; off; off >>= 1) v += __shfl_down(v, off, 64);
    __shared__ float ssum[2];
    const int lane = t & 63, w = t >> 6;
    if (lane == 0) ssum[w] = v;
    __syncthreads();
    const float p = ssum[0] + ssum[1];
    if (t == 0) o_pred[b] = p;
    if (t < 16) {
        int aid = (int)rintf(p);
        aid = aid < 0 ? 0 : (aid > 15 ? 15 : aid);
        o_logits[b * 16 + t] = (t == aid) ? 1.0f : 0.0f;
    }
}

// ---------------------------------------------------------------------------
extern "C" void kernel_launch(void* const* d_in, const int* in_sizes, int n_in,
                              void* d_out, int out_size, void* d_ws, size_t ws_size,
                              hipStream_t stream)
{
    const float* v_emb = (const float*)d_in[0];
    const float* W1    = (const float*)d_in[1];
    const float* b1    = (const float*)d_in[2];
    const float* gamma = (const float*)d_in[3];
    const float* beta  = (const float*)d_in[4];
    const float* W2    = (const float*)d_in[5];
    const float* b2    = (const float*)d_in[6];

    char* ws = (char*)d_ws;
    size_t off = 0;
    bf16*  Wp   = (bf16*)(ws + off);  off += (size_t)II * HH * 2;      // 2.36 MB
    float* gw   = (float*)(ws + off); off += (size_t)II * 4;
    float* scal = (float*)(ws + off); off += 256;
    float* part = (float*)(ws + off); off += (size_t)MM * 36 * 4;      // 7.37 MB
    bf16*  Av   = (bf16*)(ws + off);  off += (size_t)MM * HH * 2;      // 78.6 MB

    float* out       = (float*)d_out;
    float* o_scores  = out;            // 51200
    float* o_pred    = out + MM;       // 512
    float* o_logits  = out + MM + BB;  // 8192

    hipLaunchKernelGGL(prep_conv, dim3(19778), dim3(256), 0, stream,
                       v_emb, W1, gamma, beta, W2, b2, Av, Wp, gw, scal);
    hipLaunchKernelGGL(gemm_part, dim3((MM / 128) * 12), dim3(256),
                       0, stream, Av, Wp, b1, gw, part);
    hipLaunchKernelGGL(score_pred, dim3(BB), dim3(128), 0, stream,
                       part, scal, o_scores, o_pred, o_logits);
}